// Round 3
// baseline (1560.387 us; speedup 1.0000x reference)
//
#include <hip/hip_runtime.h>
#include <hip/hip_bf16.h>
#include <math.h>

#define DD 768
#define HH 384
#define BB 16
#define TT 1024
#define NIH 1152
#define GSP 3   // workgroups per batch in the GRU scan

typedef __attribute__((ext_vector_type(8))) short short8;
typedef __attribute__((ext_vector_type(8))) __bf16 bf16x8;
typedef __attribute__((ext_vector_type(4))) float f32x4;

static __device__ __forceinline__ unsigned short f2bf(float f) {
  unsigned u = __float_as_uint(f);
  u += 0x7fffu + ((u >> 16) & 1u);          // RNE
  return (unsigned short)(u >> 16);
}
static __device__ __forceinline__ float bf2f(unsigned short h) {
  return __uint_as_float(((unsigned)h) << 16);
}

// ---------------- k1a: weight conversion + barrier-counter reset ----------------
__global__ void prep_convert(const float* __restrict__ wgw, const float* __restrict__ wih,
                             const float* __restrict__ whh,
                             unsigned short* __restrict__ wgw_bf, unsigned short* __restrict__ wih_bf,
                             unsigned short* __restrict__ whh_bf, unsigned* __restrict__ cnt)
{
  if (blockIdx.x == 0 && threadIdx.x < 256) cnt[threadIdx.x] = 0;
  const int n1 = DD*DD, n2 = NIH*DD, n3 = NIH*HH;
  int stride = gridDim.x * 256;
  for (int idx = blockIdx.x*256 + threadIdx.x; idx < n1+n2+n3; idx += stride) {
    if (idx < n1)            wgw_bf[idx]       = f2bf(wgw[idx]);
    else if (idx < n1+n2)    wih_bf[idx-n1]    = f2bf(wih[idx-n1]);
    else                     whh_bf[idx-n1-n2] = f2bf(whh[idx-n1-n2]);
  }
}

// ---------------- k1b: vL = Wg_w^T aL, vR = Wg_w^T aR, c0/c1 ----------------
__global__ void prep_vecs(const float* __restrict__ wgw, const float* __restrict__ wgb,
                          const float* __restrict__ aL, const float* __restrict__ aR,
                          float* __restrict__ vLR, float* __restrict__ c01)
{
  int tid = threadIdx.x;
  if (blockIdx.x < 3) {
    int j = blockIdx.x*256 + tid;   // 0..767
    float al = 0.f, ar = 0.f;
    for (int i = 0; i < DD; ++i) { float wv = wgw[i*DD + j]; al += wv*aL[i]; ar += wv*aR[i]; }
    vLR[j] = al; vLR[DD + j] = ar;
  } else {
    float al = 0.f, ar = 0.f;
    for (int i = tid; i < DD; i += 256) { float bv = wgb[i]; al += bv*aL[i]; ar += bv*aR[i]; }
    for (int off = 32; off; off >>= 1) { al += __shfl_down(al, off); ar += __shfl_down(ar, off); }
    __shared__ float red[8];
    int w = tid >> 6, l = tid & 63;
    if (l == 0) { red[w*2] = al; red[w*2+1] = ar; }
    __syncthreads();
    if (tid == 0) { c01[0] = red[0]+red[2]+red[4]+red[6]; c01[1] = red[1]+red[3]+red[5]+red[7]; }
  }
}

// ---------------- k2: exact f32 attention scores ----------------
__global__ __launch_bounds__(256) void scores_cvt(const float* __restrict__ emb,
    const float* __restrict__ vLR, const float* __restrict__ c01,
    float* __restrict__ ss, float* __restrict__ sr)
{
  int row = blockIdx.x, tid = threadIdx.x;
  const float* er = emb + (size_t)row*DD;
  float al = 0.f, ar = 0.f;
  for (int d = tid; d < DD; d += 256) {
    float e = er[d];
    al += e*vLR[d]; ar += e*vLR[DD+d];
  }
  for (int off = 32; off; off >>= 1) { al += __shfl_down(al, off); ar += __shfl_down(ar, off); }
  __shared__ float red[8];
  int w = tid >> 6, l = tid & 63;
  if (l == 0) { red[w*2] = al; red[w*2+1] = ar; }
  __syncthreads();
  if (tid == 0) {
    ss[row] = red[0]+red[2]+red[4]+red[6] + c01[0];
    sr[row] = red[1]+red[3]+red[5]+red[7] + c01[1];
  }
}

// ---------------- GEMM: C[m,n] = sum_k A[m,k]*Bw[n,k] + bias[n] ----------------
// A is f32 (AF32=true, converted on the fly) or bf16. Bw bf16, C bf16.
// 128x128 tile, BK=32, 4 waves, reg-staged LDS, XOR-swizzled chunks.
template<bool AF32>
__global__ __launch_bounds__(256) void gemm_bt(const void* __restrict__ Av,
    const unsigned short* __restrict__ Bw, const float* __restrict__ bias,
    unsigned short* __restrict__ C, int N, int MT, int Mreal)
{
  __shared__ __align__(16) unsigned short As[128][32];
  __shared__ __align__(16) unsigned short Bs[128][32];
  int tid = threadIdx.x;
  int tm = blockIdx.x % MT, tn = blockIdx.x / MT;
  int l = tid & 63, lr = l & 15, lk = l >> 4;
  int w = tid >> 6;
  int wm = (w >> 1)*64, wn = (w & 1)*64;
  f32x4 acc[4][4] = {};

  int c0 = tid, c1 = tid + 256;            // 512 16B-chunks per tile
  int r0 = c0 >> 2, ch0 = c0 & 3;
  int r1 = c1 >> 2, ch1 = c1 & 3;
  const unsigned short* Bbase = Bw + (size_t)tn*128*DD;

  for (int kt = 0; kt < 24; ++kt) {
    short8 va0, va1;
    if constexpr (AF32) {
      const float* Af = (const float*)Av + (size_t)tm*128*DD;
      f32x4 a0l = *(const f32x4*)(Af + r0*DD + kt*32 + ch0*8);
      f32x4 a0h = *(const f32x4*)(Af + r0*DD + kt*32 + ch0*8 + 4);
      f32x4 a1l = *(const f32x4*)(Af + r1*DD + kt*32 + ch1*8);
      f32x4 a1h = *(const f32x4*)(Af + r1*DD + kt*32 + ch1*8 + 4);
      #pragma unroll
      for (int j = 0; j < 4; ++j) {
        va0[j] = (short)f2bf(a0l[j]); va0[4+j] = (short)f2bf(a0h[j]);
        va1[j] = (short)f2bf(a1l[j]); va1[4+j] = (short)f2bf(a1h[j]);
      }
    } else {
      const unsigned short* Ab = (const unsigned short*)Av + (size_t)tm*128*DD;
      va0 = *(const short8*)(Ab + r0*DD + kt*32 + ch0*8);
      va1 = *(const short8*)(Ab + r1*DD + kt*32 + ch1*8);
    }
    short8 vb0 = *(const short8*)(Bbase + r0*DD + kt*32 + ch0*8);
    short8 vb1 = *(const short8*)(Bbase + r1*DD + kt*32 + ch1*8);
    __syncthreads();                        // previous compute done
    *(short8*)&As[r0][(ch0 ^ (r0&3))*8] = va0;
    *(short8*)&As[r1][(ch1 ^ (r1&3))*8] = va1;
    *(short8*)&Bs[r0][(ch0 ^ (r0&3))*8] = vb0;
    *(short8*)&Bs[r1][(ch1 ^ (r1&3))*8] = vb1;
    __syncthreads();
    bf16x8 af[4], bfr[4];
    #pragma unroll
    for (int mi = 0; mi < 4; ++mi) {
      int r = wm + mi*16 + lr;
      af[mi] = __builtin_bit_cast(bf16x8, *(const short8*)&As[r][(lk ^ (lr&3))*8]);
    }
    #pragma unroll
    for (int ni = 0; ni < 4; ++ni) {
      int r = wn + ni*16 + lr;
      bfr[ni] = __builtin_bit_cast(bf16x8, *(const short8*)&Bs[r][(lk ^ (lr&3))*8]);
    }
    #pragma unroll
    for (int mi = 0; mi < 4; ++mi)
      #pragma unroll
      for (int ni = 0; ni < 4; ++ni)
        acc[mi][ni] = __builtin_amdgcn_mfma_f32_16x16x32_bf16(af[mi], bfr[ni], acc[mi][ni], 0, 0, 0);
  }
  // epilogue: D layout col=lane&15, row=(lane>>4)*4+reg
  for (int mi = 0; mi < 4; ++mi) {
    int rbase = tm*128 + wm + mi*16 + lk*4;
    for (int ni = 0; ni < 4; ++ni) {
      int col = tn*128 + wn + ni*16 + lr;
      float bv = bias[col];
      #pragma unroll
      for (int jr = 0; jr < 4; ++jr) {
        int row = rbase + jr;
        if (row < Mreal) C[(size_t)row*N + col] = f2bf(acc[mi][ni][jr] + bv);
      }
    }
  }
}

// ---------------- k4: GAT attention (exact f32 scores) + build G_W (bf16) ----------------
__global__ __launch_bounds__(256) void gat_attn(const float* __restrict__ emb,
    const float* __restrict__ cls, const unsigned short* __restrict__ wgt_bf,
    const float* __restrict__ ss, const float* __restrict__ sr,
    const int* __restrict__ cidx, const int* __restrict__ cmask,
    unsigned short* __restrict__ gw_bf)
{
  int bx = blockIdx.x, tid = threadIdx.x;
  if (bx >= BB*TT) {                       // CLS rows
    int b = bx - BB*TT;
    unsigned short* dst = gw_bf + (size_t)(b*(TT+1))*DD;
    for (int d = tid; d < DD; d += 256) dst[d] = f2bf(cls[d]);
    return;
  }
  int b = bx >> 10, t = bx & 1023;
  __shared__ float sw[8];
  __shared__ int   si[8];
  __shared__ int   sm[8];
  if (tid < 8) {
    int ci = cidx[(size_t)bx*8 + tid];
    int cm = cmask[(size_t)bx*8 + tid];
    float s = ss[bx] + sr[(b<<10) + ci];
    s = s > 0.f ? s : 0.2f*s;              // leaky_relu(0.2)
    sw[tid] = cm ? s : -1e9f;
    si[tid] = ci;
    sm[tid] = cm;
  }
  __syncthreads();
  float a[8];
  float mx = -1e30f;
  #pragma unroll
  for (int k = 0; k < 8; ++k) mx = fmaxf(mx, sw[k]);
  float sum = 0.f;
  #pragma unroll
  for (int k = 0; k < 8; ++k) { a[k] = expf(sw[k]-mx); sum += a[k]; }
  float inv = 1.f/sum;
  #pragma unroll
  for (int k = 0; k < 8; ++k) a[k] = sm[k] ? a[k]*inv : 0.f;
  const float* er = emb + (size_t)bx*DD;
  unsigned short* dst = gw_bf + (size_t)(b*(TT+1) + t + 1)*DD;
  for (int d = tid; d < DD; d += 256) {
    float acc = er[d];
    #pragma unroll
    for (int k = 0; k < 8; ++k)
      if (a[k] != 0.f) acc += a[k]*bf2f(wgt_bf[((size_t)(b<<10) + si[k])*DD + d]);
    dst[d] = f2bf(acc);
  }
}

// ---------------- k6: GRU scan. 3 WGs per batch (same XCD); Whh slice in VGPRs ----------------
__global__ __launch_bounds__(512, 2) void gru_scan(const unsigned short* __restrict__ whh_bf,
    const float* __restrict__ bhh, const unsigned short* __restrict__ xp,
    const int* __restrict__ clue, float* __restrict__ hbuf, unsigned* __restrict__ cnt,
    float* __restrict__ hfinal)
{
  __shared__ __align__(16) unsigned short h_bf[HH];
  __shared__ __align__(16) float y_s[HH];
  __shared__ float bhh_s[HH];
  __shared__ unsigned char m_s[TT+1];
  int tid = threadIdx.x;
  // blocks b, b+16, b+32 land on the same XCD under round-robin dispatch
  int b = blockIdx.x % BB, g = blockIdx.x / BB;
  int w = tid >> 6, l = tid & 63, lr = l & 15, lk = l >> 4;

  // permanently load this wave's 3 row-groups x 12 k-chunks of Whh as A-fragments
  bf16x8 areg[3][12];
  #pragma unroll
  for (int i = 0; i < 3; ++i) {
    int nt = w*3 + i;                       // 0..23 (8 per gate)
    int gate = nt >> 3;
    int il = (nt & 7)*16 + lr;
    const unsigned short* src = whh_bf + (size_t)(gate*HH + g*128 + il)*HH;
    #pragma unroll
    for (int kt = 0; kt < 12; ++kt)
      areg[i][kt] = __builtin_bit_cast(bf16x8, *(const short8*)(src + kt*32 + lk*8));
  }
  if (tid < HH) {
    int gate = tid >> 7, il = tid & 127;
    bhh_s[tid] = bhh[gate*HH + g*128 + il];
    h_bf[tid] = 0;
  }
  for (int t = tid; t < TT; t += 512) m_s[t+1] = (clue[b*TT + t] != 0) ? 1 : 0;
  if (tid == 0) m_s[0] = 1;
  __syncthreads();

  float h_prev = 0.f;                       // this thread's own h element (tid<128)
  int s = 0;
  unsigned* cb = cnt + b*16;                // padded counter, one 64B line per batch
  for (int t = 0; t <= TT; ++t) {
    if (!m_s[t]) continue;                  // masked step: h unchanged, skip entirely
    ++s;
    float xr = 0.f, xz = 0.f, xn = 0.f;
    if (tid < 128) {                        // prefetch x_proj early (hidden by MFMA)
      const unsigned short* xrow = xp + (size_t)(b*(TT+1) + t)*NIH;
      int gi = g*128 + tid;
      xr = bf2f(xrow[gi]); xz = bf2f(xrow[HH + gi]); xn = bf2f(xrow[2*HH + gi]);
    }
    // hp = Whh_slice @ h  (B = h replicated across 16 cols; D cols all equal)
    f32x4 acc[3] = {};
    #pragma unroll
    for (int kt = 0; kt < 12; ++kt) {
      bf16x8 bfr = __builtin_bit_cast(bf16x8, *(const short8*)&h_bf[kt*32 + lk*8]);
      #pragma unroll
      for (int i = 0; i < 3; ++i)
        acc[i] = __builtin_amdgcn_mfma_f32_16x16x32_bf16(areg[i][kt], bfr, acc[i], 0, 0, 0);
    }
    if (lr == 0) {
      #pragma unroll
      for (int i = 0; i < 3; ++i)
        *(f32x4*)&y_s[(w*3+i)*16 + lk*4] = acc[i];
    }
    __syncthreads();
    if (tid < 128) {
      int il = tid, gi = g*128 + il;
      float hr = y_s[il]       + bhh_s[il];
      float hz = y_s[128+il]   + bhh_s[128+il];
      float hn = y_s[256+il]   + bhh_s[256+il];
      float rg = 1.f/(1.f + expf(-(xr + hr)));
      float zg = 1.f/(1.f + expf(-(xz + hz)));
      float ng = tanhf(xn + rg*hn);
      float hnew = (1.f - zg)*ng + zg*h_prev;
      h_prev = hnew;
      __hip_atomic_store(hbuf + ((size_t)(s&1)*BB + b)*HH + gi, hnew,
                         __ATOMIC_RELAXED, __HIP_MEMORY_SCOPE_AGENT);
    }
    __syncthreads();                        // drains vmcnt: stores visible at coherence point
    if (tid == 0) {
      __hip_atomic_fetch_add(cb, 1u, __ATOMIC_RELEASE, __HIP_MEMORY_SCOPE_AGENT);
      unsigned tgt = (unsigned)(GSP*s);
      while (__hip_atomic_load(cb, __ATOMIC_ACQUIRE, __HIP_MEMORY_SCOPE_AGENT) < tgt)
        __builtin_amdgcn_s_sleep(1);
    }
    __syncthreads();
    if (tid < HH) {
      float hv = __hip_atomic_load(hbuf + ((size_t)(s&1)*BB + b)*HH + tid,
                                   __ATOMIC_RELAXED, __HIP_MEMORY_SCOPE_AGENT);
      h_bf[tid] = f2bf(hv);
    }
    __syncthreads();
  }
  if (g == 0 && tid < HH) {
    float hv = __hip_atomic_load(hbuf + ((size_t)(s&1)*BB + b)*HH + tid,
                                 __ATOMIC_RELAXED, __HIP_MEMORY_SCOPE_AGENT);
    hfinal[b*HH + tid] = hv;
  }
}

// ---------------- k6b: per-batch head contribution of h_clue ----------------
__global__ __launch_bounds__(384) void hpart_k(const float* __restrict__ hfinal,
    const float* __restrict__ Wc, const float* __restrict__ Wcb,
    const float* __restrict__ We, const float* __restrict__ Web, float* __restrict__ hpart)
{
  int b = blockIdx.x, tid = threadIdx.x;
  int j = tid >> 6, l = tid & 63;
  const float* wr = ((j < 3) ? (Wc + j*NIH) : (We + (j-3)*NIH)) + DD;
  float acc = 0.f;
  #pragma unroll
  for (int i = 0; i < 6; ++i) acc += hfinal[b*HH + l + i*64] * wr[l + i*64];
  for (int off = 32; off; off >>= 1) acc += __shfl_down(acc, off);
  if (l == 0) hpart[b*6 + j] = acc + ((j < 3) ? Wcb[j] : Web[j-3]);
}

// ---------------- k7: cause/effect heads ----------------
__global__ __launch_bounds__(256) void heads(const unsigned short* __restrict__ gw_bf,
    const float* __restrict__ Wc, const float* __restrict__ We,
    const float* __restrict__ hpart, float* __restrict__ out)
{
  __shared__ float Wl[6][DD];
  int tid = threadIdx.x;
  for (int idx = tid; idx < 6*DD; idx += 256) {
    int j = idx / DD, d = idx % DD;
    Wl[j][d] = (j < 3) ? Wc[j*NIH + d] : We[(j-3)*NIH + d];
  }
  __syncthreads();
  int w = tid >> 6, l = tid & 63;
  int row = blockIdx.x*4 + w;
  int b = row >> 10, t = row & 1023;
  const unsigned short* gr = gw_bf + (size_t)(b*(TT+1) + t + 1)*DD;
  float acc[6] = {0,0,0,0,0,0};
  for (int i = 0; i < 12; ++i) {
    int d = l + i*64;
    float v = bf2f(gr[d]);
    #pragma unroll
    for (int j = 0; j < 6; ++j) acc[j] += v * Wl[j][d];
  }
  #pragma unroll
  for (int j = 0; j < 6; ++j)
    for (int off = 32; off; off >>= 1) acc[j] += __shfl_down(acc[j], off);
  if (l == 0) {
    const float* hp = hpart + b*6;
    float* oc = out + (size_t)b*TT*3 + t*3;
    float* oe = out + (size_t)BB*TT*3 + (size_t)b*TT*3 + t*3;
    oc[0] = acc[0]+hp[0]; oc[1] = acc[1]+hp[1]; oc[2] = acc[2]+hp[2];
    oe[0] = acc[3]+hp[3]; oe[1] = acc[4]+hp[4]; oe[2] = acc[5]+hp[5];
  }
}

extern "C" void kernel_launch(void* const* d_in, const int* in_sizes, int n_in,
                              void* d_out, int out_size, void* d_ws, size_t ws_size,
                              hipStream_t stream)
{
  const float* emb  = (const float*)d_in[0];
  const float* cls  = (const float*)d_in[1];
  const float* wgw  = (const float*)d_in[2];
  const float* wgb  = (const float*)d_in[3];
  const float* aL   = (const float*)d_in[4];
  const float* aR   = (const float*)d_in[5];
  const float* wih  = (const float*)d_in[6];
  const float* bih  = (const float*)d_in[7];
  const float* whh  = (const float*)d_in[8];
  const float* bhh  = (const float*)d_in[9];
  const float* wcw  = (const float*)d_in[10];
  const float* wcb  = (const float*)d_in[11];
  const float* wew  = (const float*)d_in[12];
  const float* web  = (const float*)d_in[13];
  const int* cidx   = (const int*)d_in[14];
  const int* cmask  = (const int*)d_in[15];
  const int* clue   = (const int*)d_in[16];
  (void)in_sizes; (void)n_in; (void)out_size; (void)ws_size;

  char* ws = (char*)d_ws;
  size_t off = 0;
  auto alloc = [&](size_t bytes) { char* p = ws + off; off += (bytes + 255) & ~(size_t)255; return p; };
  // regionA: xp_bf (38MB); wgt_bf (25.2MB) aliases its head — disjoint lifetimes
  unsigned short* xp_bf  = (unsigned short*)alloc((size_t)16512*1152*2);
  unsigned short* wgt_bf = xp_bf;
  unsigned short* gw_bf  = (unsigned short*)alloc((size_t)16512*768*2);   // 129*128 rows padded
  unsigned short* wgw_bf = (unsigned short*)alloc((size_t)768*768*2);
  unsigned short* wih_bf = (unsigned short*)alloc((size_t)1152*768*2);
  unsigned short* whh_bf = (unsigned short*)alloc((size_t)1152*384*2);
  float* vLR   = (float*)alloc(1536*4);
  float* c01   = (float*)alloc(256);
  float* ss    = (float*)alloc(16384*4);
  float* sr    = (float*)alloc(16384*4);
  float* hbuf  = (float*)alloc((size_t)2*16*384*4);
  float* hfin  = (float*)alloc((size_t)16*384*4);
  float* hpart = (float*)alloc(512);
  unsigned* cnt = (unsigned*)alloc(256*4);

  prep_convert<<<2048, 256, 0, stream>>>(wgw, wih, whh, wgw_bf, wih_bf, whh_bf, cnt);
  prep_vecs<<<4, 256, 0, stream>>>(wgw, wgb, aL, aR, vLR, c01);
  scores_cvt<<<16384, 256, 0, stream>>>(emb, vLR, c01, ss, sr);
  gemm_bt<true><<<128*6, 256, 0, stream>>>(emb, wgw_bf, wgb, wgt_bf, 768, 128, 16384);
  gat_attn<<<16384+16, 256, 0, stream>>>(emb, cls, wgt_bf, ss, sr, cidx, cmask, gw_bf);
  gemm_bt<false><<<129*9, 256, 0, stream>>>(gw_bf, wih_bf, bih, xp_bf, 1152, 129, 16400);
  gru_scan<<<BB*GSP, 512, 0, stream>>>(whh_bf, bhh, xp_bf, clue, hbuf, cnt, hfin);
  hpart_k<<<16, 384, 0, stream>>>(hfin, wcw, wcb, wew, web, hpart);
  heads<<<4096, 256, 0, stream>>>(gw_bf, wcw, wew, hpart, (float*)d_out);
}

// Round 4
// 1031.091 us; speedup vs baseline: 1.5133x; 1.5133x over previous
//
#include <hip/hip_runtime.h>
#include <hip/hip_bf16.h>
#include <math.h>

#define DD 768
#define HH 384
#define BB 16
#define TT 1024
#define NIH 1152
#define GSP 3   // workgroups per batch in the GRU scan

typedef __attribute__((ext_vector_type(8))) short short8;
typedef __attribute__((ext_vector_type(8))) __bf16 bf16x8;
typedef __attribute__((ext_vector_type(4))) float f32x4;

static __device__ __forceinline__ unsigned short f2bf(float f) {
  unsigned u = __float_as_uint(f);
  u += 0x7fffu + ((u >> 16) & 1u);          // RNE
  return (unsigned short)(u >> 16);
}
static __device__ __forceinline__ float bf2f(unsigned short h) {
  return __uint_as_float(((unsigned)h) << 16);
}

// ---------------- k1a: weight conversion ----------------
__global__ void prep_convert(const float* __restrict__ wgw, const float* __restrict__ wih,
                             const float* __restrict__ whh,
                             unsigned short* __restrict__ wgw_bf, unsigned short* __restrict__ wih_bf,
                             unsigned short* __restrict__ whh_bf)
{
  const int n1 = DD*DD, n2 = NIH*DD, n3 = NIH*HH;
  int stride = gridDim.x * 256;
  for (int idx = blockIdx.x*256 + threadIdx.x; idx < n1+n2+n3; idx += stride) {
    if (idx < n1)            wgw_bf[idx]       = f2bf(wgw[idx]);
    else if (idx < n1+n2)    wih_bf[idx-n1]    = f2bf(wih[idx-n1]);
    else                     whh_bf[idx-n1-n2] = f2bf(whh[idx-n1-n2]);
  }
}

// ---------------- k1b: vL = Wg_w^T aL, vR = Wg_w^T aR, c0/c1 ----------------
__global__ void prep_vecs(const float* __restrict__ wgw, const float* __restrict__ wgb,
                          const float* __restrict__ aL, const float* __restrict__ aR,
                          float* __restrict__ vLR, float* __restrict__ c01)
{
  int tid = threadIdx.x;
  if (blockIdx.x < 3) {
    int j = blockIdx.x*256 + tid;   // 0..767
    float al = 0.f, ar = 0.f;
    for (int i = 0; i < DD; ++i) { float wv = wgw[i*DD + j]; al += wv*aL[i]; ar += wv*aR[i]; }
    vLR[j] = al; vLR[DD + j] = ar;
  } else {
    float al = 0.f, ar = 0.f;
    for (int i = tid; i < DD; i += 256) { float bv = wgb[i]; al += bv*aL[i]; ar += bv*aR[i]; }
    for (int off = 32; off; off >>= 1) { al += __shfl_down(al, off); ar += __shfl_down(ar, off); }
    __shared__ float red[8];
    int w = tid >> 6, l = tid & 63;
    if (l == 0) { red[w*2] = al; red[w*2+1] = ar; }
    __syncthreads();
    if (tid == 0) { c01[0] = red[0]+red[2]+red[4]+red[6]; c01[1] = red[1]+red[3]+red[5]+red[7]; }
  }
}

// ---------------- k2: exact f32 attention scores ----------------
__global__ __launch_bounds__(256) void scores_cvt(const float* __restrict__ emb,
    const float* __restrict__ vLR, const float* __restrict__ c01,
    float* __restrict__ ss, float* __restrict__ sr)
{
  int row = blockIdx.x, tid = threadIdx.x;
  const float* er = emb + (size_t)row*DD;
  float al = 0.f, ar = 0.f;
  for (int d = tid; d < DD; d += 256) {
    float e = er[d];
    al += e*vLR[d]; ar += e*vLR[DD+d];
  }
  for (int off = 32; off; off >>= 1) { al += __shfl_down(al, off); ar += __shfl_down(ar, off); }
  __shared__ float red[8];
  int w = tid >> 6, l = tid & 63;
  if (l == 0) { red[w*2] = al; red[w*2+1] = ar; }
  __syncthreads();
  if (tid == 0) {
    ss[row] = red[0]+red[2]+red[4]+red[6] + c01[0];
    sr[row] = red[1]+red[3]+red[5]+red[7] + c01[1];
  }
}

// ---------------- GEMM: C[m,n] = sum_k A[m,k]*Bw[n,k] + bias[n] ----------------
// A is f32 (AF32=true, converted on the fly) or bf16. Bw bf16, C bf16.
// 128x128 tile, BK=32, 4 waves, reg-staged LDS, XOR-swizzled chunks.
template<bool AF32>
__global__ __launch_bounds__(256) void gemm_bt(const void* __restrict__ Av,
    const unsigned short* __restrict__ Bw, const float* __restrict__ bias,
    unsigned short* __restrict__ C, int N, int MT, int Mreal)
{
  __shared__ __align__(16) unsigned short As[128][32];
  __shared__ __align__(16) unsigned short Bs[128][32];
  int tid = threadIdx.x;
  int tm = blockIdx.x % MT, tn = blockIdx.x / MT;
  int l = tid & 63, lr = l & 15, lk = l >> 4;
  int w = tid >> 6;
  int wm = (w >> 1)*64, wn = (w & 1)*64;
  f32x4 acc[4][4] = {};

  int c0 = tid, c1 = tid + 256;            // 512 16B-chunks per tile
  int r0 = c0 >> 2, ch0 = c0 & 3;
  int r1 = c1 >> 2, ch1 = c1 & 3;
  const unsigned short* Bbase = Bw + (size_t)tn*128*DD;

  for (int kt = 0; kt < 24; ++kt) {
    short8 va0, va1;
    if constexpr (AF32) {
      const float* Af = (const float*)Av + (size_t)tm*128*DD;
      f32x4 a0l = *(const f32x4*)(Af + r0*DD + kt*32 + ch0*8);
      f32x4 a0h = *(const f32x4*)(Af + r0*DD + kt*32 + ch0*8 + 4);
      f32x4 a1l = *(const f32x4*)(Af + r1*DD + kt*32 + ch1*8);
      f32x4 a1h = *(const f32x4*)(Af + r1*DD + kt*32 + ch1*8 + 4);
      #pragma unroll
      for (int j = 0; j < 4; ++j) {
        va0[j] = (short)f2bf(a0l[j]); va0[4+j] = (short)f2bf(a0h[j]);
        va1[j] = (short)f2bf(a1l[j]); va1[4+j] = (short)f2bf(a1h[j]);
      }
    } else {
      const unsigned short* Ab = (const unsigned short*)Av + (size_t)tm*128*DD;
      va0 = *(const short8*)(Ab + r0*DD + kt*32 + ch0*8);
      va1 = *(const short8*)(Ab + r1*DD + kt*32 + ch1*8);
    }
    short8 vb0 = *(const short8*)(Bbase + r0*DD + kt*32 + ch0*8);
    short8 vb1 = *(const short8*)(Bbase + r1*DD + kt*32 + ch1*8);
    __syncthreads();                        // previous compute done
    *(short8*)&As[r0][(ch0 ^ (r0&3))*8] = va0;
    *(short8*)&As[r1][(ch1 ^ (r1&3))*8] = va1;
    *(short8*)&Bs[r0][(ch0 ^ (r0&3))*8] = vb0;
    *(short8*)&Bs[r1][(ch1 ^ (r1&3))*8] = vb1;
    __syncthreads();
    bf16x8 af[4], bfr[4];
    #pragma unroll
    for (int mi = 0; mi < 4; ++mi) {
      int r = wm + mi*16 + lr;
      af[mi] = __builtin_bit_cast(bf16x8, *(const short8*)&As[r][(lk ^ (lr&3))*8]);
    }
    #pragma unroll
    for (int ni = 0; ni < 4; ++ni) {
      int r = wn + ni*16 + lr;
      bfr[ni] = __builtin_bit_cast(bf16x8, *(const short8*)&Bs[r][(lk ^ (lr&3))*8]);
    }
    #pragma unroll
    for (int mi = 0; mi < 4; ++mi)
      #pragma unroll
      for (int ni = 0; ni < 4; ++ni)
        acc[mi][ni] = __builtin_amdgcn_mfma_f32_16x16x32_bf16(af[mi], bfr[ni], acc[mi][ni], 0, 0, 0);
  }
  // epilogue: D layout col=lane&15, row=(lane>>4)*4+reg
  for (int mi = 0; mi < 4; ++mi) {
    int rbase = tm*128 + wm + mi*16 + lk*4;
    for (int ni = 0; ni < 4; ++ni) {
      int col = tn*128 + wn + ni*16 + lr;
      float bv = bias[col];
      #pragma unroll
      for (int jr = 0; jr < 4; ++jr) {
        int row = rbase + jr;
        if (row < Mreal) C[(size_t)row*N + col] = f2bf(acc[mi][ni][jr] + bv);
      }
    }
  }
}

// ---------------- k4: GAT attention (exact f32 scores) + build G_W (bf16) ----------------
__global__ __launch_bounds__(256) void gat_attn(const float* __restrict__ emb,
    const float* __restrict__ cls, const unsigned short* __restrict__ wgt_bf,
    const float* __restrict__ ss, const float* __restrict__ sr,
    const int* __restrict__ cidx, const int* __restrict__ cmask,
    unsigned short* __restrict__ gw_bf)
{
  int bx = blockIdx.x, tid = threadIdx.x;
  if (bx >= BB*TT) {                       // CLS rows
    int b = bx - BB*TT;
    unsigned short* dst = gw_bf + (size_t)(b*(TT+1))*DD;
    for (int d = tid; d < DD; d += 256) dst[d] = f2bf(cls[d]);
    return;
  }
  int b = bx >> 10, t = bx & 1023;
  __shared__ float sw[8];
  __shared__ int   si[8];
  __shared__ int   sm[8];
  if (tid < 8) {
    int ci = cidx[(size_t)bx*8 + tid];
    int cm = cmask[(size_t)bx*8 + tid];
    float s = ss[bx] + sr[(b<<10) + ci];
    s = s > 0.f ? s : 0.2f*s;              // leaky_relu(0.2)
    sw[tid] = cm ? s : -1e9f;
    si[tid] = ci;
    sm[tid] = cm;
  }
  __syncthreads();
  float a[8];
  float mx = -1e30f;
  #pragma unroll
  for (int k = 0; k < 8; ++k) mx = fmaxf(mx, sw[k]);
  float sum = 0.f;
  #pragma unroll
  for (int k = 0; k < 8; ++k) { a[k] = expf(sw[k]-mx); sum += a[k]; }
  float inv = 1.f/sum;
  #pragma unroll
  for (int k = 0; k < 8; ++k) a[k] = sm[k] ? a[k]*inv : 0.f;
  const float* er = emb + (size_t)bx*DD;
  unsigned short* dst = gw_bf + (size_t)(b*(TT+1) + t + 1)*DD;
  for (int d = tid; d < DD; d += 256) {
    float acc = er[d];
    #pragma unroll
    for (int k = 0; k < 8; ++k)
      if (a[k] != 0.f) acc += a[k]*bf2f(wgt_bf[((size_t)(b<<10) + si[k])*DD + d]);
    dst[d] = f2bf(acc);
  }
}

// ---------------- k6: GRU scan, tag-in-word exchange ----------------
// 3 WGs per batch; Whh slice lives in VGPR/AGPR MFMA A-fragments.
// Per active step s each owner thread publishes (bf16(h)<<16 | s) to a
// per-step slot (never overwritten within a run -> no ring deadlock;
// stale replay data is value-identical -> harmless). Readers spin on the
// tag with relaxed agent loads: exactly one wire round-trip per step.
__global__ __launch_bounds__(512, 2) void gru_scan(const unsigned short* __restrict__ whh_bf,
    const float* __restrict__ bhh, const unsigned short* __restrict__ xp,
    const int* __restrict__ clue, unsigned* __restrict__ hbuf,
    float* __restrict__ hfinal)
{
  __shared__ __align__(16) unsigned short h_bf[HH];
  __shared__ __align__(16) float y_s[HH];
  __shared__ float bhh_s[HH];
  __shared__ unsigned char m_s[TT+1];
  int tid = threadIdx.x;
  // blocks b, b+16, b+32 land on the same XCD under round-robin dispatch
  int b = blockIdx.x % BB, g = blockIdx.x / BB;
  int w = tid >> 6, l = tid & 63, lr = l & 15, lk = l >> 4;

  // permanently load this wave's 3 row-groups x 12 k-chunks of Whh as A-fragments
  bf16x8 areg[3][12];
  #pragma unroll
  for (int i = 0; i < 3; ++i) {
    int nt = w*3 + i;                       // 0..23 (8 per gate)
    int gate = nt >> 3;
    int il = (nt & 7)*16 + lr;
    const unsigned short* src = whh_bf + (size_t)(gate*HH + g*128 + il)*HH;
    #pragma unroll
    for (int kt = 0; kt < 12; ++kt)
      areg[i][kt] = __builtin_bit_cast(bf16x8, *(const short8*)(src + kt*32 + lk*8));
  }
  if (tid < HH) {
    int gate = tid >> 7, il = tid & 127;
    bhh_s[tid] = bhh[gate*HH + g*128 + il];
    h_bf[tid] = 0;
  }
  for (int t = tid; t < TT; t += 512) m_s[t+1] = (clue[b*TT + t] != 0) ? 1 : 0;
  if (tid == 0) m_s[0] = 1;
  __syncthreads();

  float h_prev = 0.f;                       // this thread's own h element (tid<128)
  int s = 0;
  int rj = (g*128 + 128 + tid) % HH;        // remote element for reader tid<256
  for (int t = 0; t <= TT; ++t) {
    if (!m_s[t]) continue;                  // masked step: h unchanged, skip entirely
    ++s;
    float xr = 0.f, xz = 0.f, xn = 0.f;
    if (tid < 128) {                        // x_proj loads hidden under MFMA
      const unsigned short* xrow = xp + (size_t)(b*(TT+1) + t)*NIH;
      int gi = g*128 + tid;
      xr = bf2f(xrow[gi]); xz = bf2f(xrow[HH + gi]); xn = bf2f(xrow[2*HH + gi]);
    }
    // hp = Whh_slice @ h  (B = h replicated across 16 cols; D cols all equal)
    f32x4 acc[3] = {};
    #pragma unroll
    for (int kt = 0; kt < 12; ++kt) {
      bf16x8 bfr = __builtin_bit_cast(bf16x8, *(const short8*)&h_bf[kt*32 + lk*8]);
      #pragma unroll
      for (int i = 0; i < 3; ++i)
        acc[i] = __builtin_amdgcn_mfma_f32_16x16x32_bf16(areg[i][kt], bfr, acc[i], 0, 0, 0);
    }
    if (lr == 0) {
      #pragma unroll
      for (int i = 0; i < 3; ++i)
        *(f32x4*)&y_s[(w*3+i)*16 + lk*4] = acc[i];
    }
    __syncthreads();                        // y_s ready; all h_bf reads done
    unsigned* slot = hbuf + ((size_t)s*BB + b)*HH;
    if (tid < 128) {
      int il = tid, gi = g*128 + il;
      float hr = y_s[il]       + bhh_s[il];
      float hz = y_s[128+il]   + bhh_s[128+il];
      float hn = y_s[256+il]   + bhh_s[256+il];
      float rg = 1.f/(1.f + expf(-(xr + hr)));
      float zg = 1.f/(1.f + expf(-(xz + hz)));
      float ng = tanhf(xn + rg*hn);
      float hnew = (1.f - zg)*ng + zg*h_prev;
      h_prev = hnew;
      unsigned short hb16 = f2bf(hnew);
      h_bf[gi] = hb16;                      // own slice straight to LDS
      __hip_atomic_store(slot + gi, ((unsigned)hb16 << 16) | (unsigned)s,
                         __ATOMIC_RELAXED, __HIP_MEMORY_SCOPE_AGENT);
    }
    if (tid < 256) {                        // fetch 256 remote elements
      unsigned v = __hip_atomic_load(slot + rj, __ATOMIC_RELAXED, __HIP_MEMORY_SCOPE_AGENT);
      while ((v & 0xFFFFu) != (unsigned)s)
        v = __hip_atomic_load(slot + rj, __ATOMIC_RELAXED, __HIP_MEMORY_SCOPE_AGENT);
      h_bf[rj] = (unsigned short)(v >> 16);
    }
    __syncthreads();                        // h_bf[s] complete for next MFMA
  }
  if (tid < 128) hfinal[b*HH + g*128 + tid] = h_prev;   // exact f32 slice
}

// ---------------- k6b: per-batch head contribution of h_clue ----------------
__global__ __launch_bounds__(384) void hpart_k(const float* __restrict__ hfinal,
    const float* __restrict__ Wc, const float* __restrict__ Wcb,
    const float* __restrict__ We, const float* __restrict__ Web, float* __restrict__ hpart)
{
  int b = blockIdx.x, tid = threadIdx.x;
  int j = tid >> 6, l = tid & 63;
  const float* wr = ((j < 3) ? (Wc + j*NIH) : (We + (j-3)*NIH)) + DD;
  float acc = 0.f;
  #pragma unroll
  for (int i = 0; i < 6; ++i) acc += hfinal[b*HH + l + i*64] * wr[l + i*64];
  for (int off = 32; off; off >>= 1) acc += __shfl_down(acc, off);
  if (l == 0) hpart[b*6 + j] = acc + ((j < 3) ? Wcb[j] : Web[j-3]);
}

// ---------------- k7: cause/effect heads ----------------
__global__ __launch_bounds__(256) void heads(const unsigned short* __restrict__ gw_bf,
    const float* __restrict__ Wc, const float* __restrict__ We,
    const float* __restrict__ hpart, float* __restrict__ out)
{
  __shared__ float Wl[6][DD];
  int tid = threadIdx.x;
  for (int idx = tid; idx < 6*DD; idx += 256) {
    int j = idx / DD, d = idx % DD;
    Wl[j][d] = (j < 3) ? Wc[j*NIH + d] : We[(j-3)*NIH + d];
  }
  __syncthreads();
  int w = tid >> 6, l = tid & 63;
  int row = blockIdx.x*4 + w;
  int b = row >> 10, t = row & 1023;
  const unsigned short* gr = gw_bf + (size_t)(b*(TT+1) + t + 1)*DD;
  float acc[6] = {0,0,0,0,0,0};
  for (int i = 0; i < 12; ++i) {
    int d = l + i*64;
    float v = bf2f(gr[d]);
    #pragma unroll
    for (int j = 0; j < 6; ++j) acc[j] += v * Wl[j][d];
  }
  #pragma unroll
  for (int j = 0; j < 6; ++j)
    for (int off = 32; off; off >>= 1) acc[j] += __shfl_down(acc[j], off);
  if (l == 0) {
    const float* hp = hpart + b*6;
    float* oc = out + (size_t)b*TT*3 + t*3;
    float* oe = out + (size_t)BB*TT*3 + (size_t)b*TT*3 + t*3;
    oc[0] = acc[0]+hp[0]; oc[1] = acc[1]+hp[1]; oc[2] = acc[2]+hp[2];
    oe[0] = acc[3]+hp[3]; oe[1] = acc[4]+hp[4]; oe[2] = acc[5]+hp[5];
  }
}

extern "C" void kernel_launch(void* const* d_in, const int* in_sizes, int n_in,
                              void* d_out, int out_size, void* d_ws, size_t ws_size,
                              hipStream_t stream)
{
  const float* emb  = (const float*)d_in[0];
  const float* cls  = (const float*)d_in[1];
  const float* wgw  = (const float*)d_in[2];
  const float* wgb  = (const float*)d_in[3];
  const float* aL   = (const float*)d_in[4];
  const float* aR   = (const float*)d_in[5];
  const float* wih  = (const float*)d_in[6];
  const float* bih  = (const float*)d_in[7];
  const float* whh  = (const float*)d_in[8];
  const float* bhh  = (const float*)d_in[9];
  const float* wcw  = (const float*)d_in[10];
  const float* wcb  = (const float*)d_in[11];
  const float* wew  = (const float*)d_in[12];
  const float* web  = (const float*)d_in[13];
  const int* cidx   = (const int*)d_in[14];
  const int* cmask  = (const int*)d_in[15];
  const int* clue   = (const int*)d_in[16];
  (void)in_sizes; (void)n_in; (void)out_size; (void)ws_size;

  char* ws = (char*)d_ws;
  size_t off = 0;
  auto alloc = [&](size_t bytes) { char* p = ws + off; off += (bytes + 255) & ~(size_t)255; return p; };
  // regionA: xp_bf (38MB); wgt_bf (25.2MB) aliases its head — disjoint lifetimes
  unsigned short* xp_bf  = (unsigned short*)alloc((size_t)16512*1152*2);
  unsigned short* wgt_bf = xp_bf;
  unsigned short* gw_bf  = (unsigned short*)alloc((size_t)16512*768*2);   // 129*128 rows padded
  unsigned short* wgw_bf = (unsigned short*)alloc((size_t)768*768*2);
  unsigned short* wih_bf = (unsigned short*)alloc((size_t)1152*768*2);
  unsigned short* whh_bf = (unsigned short*)alloc((size_t)1152*384*2);
  float* vLR   = (float*)alloc(1536*4);
  float* c01   = (float*)alloc(256);
  float* ss    = (float*)alloc(16384*4);
  float* sr    = (float*)alloc(16384*4);
  unsigned* hbuf = (unsigned*)alloc((size_t)(TT+2)*BB*HH*4);  // per-step tagged slots, 25.2MB
  float* hfin  = (float*)alloc((size_t)16*384*4);
  float* hpart = (float*)alloc(512);

  prep_convert<<<2048, 256, 0, stream>>>(wgw, wih, whh, wgw_bf, wih_bf, whh_bf);
  prep_vecs<<<4, 256, 0, stream>>>(wgw, wgb, aL, aR, vLR, c01);
  scores_cvt<<<16384, 256, 0, stream>>>(emb, vLR, c01, ss, sr);
  gemm_bt<true><<<128*6, 256, 0, stream>>>(emb, wgw_bf, wgb, wgt_bf, 768, 128, 16384);
  gat_attn<<<16384+16, 256, 0, stream>>>(emb, cls, wgt_bf, ss, sr, cidx, cmask, gw_bf);
  gemm_bt<false><<<129*9, 256, 0, stream>>>(gw_bf, wih_bf, bih, xp_bf, 1152, 129, 16400);
  gru_scan<<<BB*GSP, 512, 0, stream>>>(whh_bf, bhh, xp_bf, clue, hbuf, hfin);
  hpart_k<<<16, 384, 0, stream>>>(hfin, wcw, wcb, wew, web, hpart);
  heads<<<4096, 256, 0, stream>>>(gw_bf, wcw, wew, hpart, (float*)d_out);
}

// Round 5
// 983.146 us; speedup vs baseline: 1.5871x; 1.0488x over previous
//
#include <hip/hip_runtime.h>
#include <hip/hip_bf16.h>
#include <math.h>

#define DD 768
#define HH 384
#define BB 16
#define TT 1024
#define NIH 1152
#define GSP 3   // workgroups per batch in the GRU scan

typedef __attribute__((ext_vector_type(8))) short short8;
typedef __attribute__((ext_vector_type(8))) __bf16 bf16x8;
typedef __attribute__((ext_vector_type(4))) float f32x4;

static __device__ __forceinline__ unsigned short f2bf(float f) {
  unsigned u = __float_as_uint(f);
  u += 0x7fffu + ((u >> 16) & 1u);          // RNE
  return (unsigned short)(u >> 16);
}
static __device__ __forceinline__ float bf2f(unsigned short h) {
  return __uint_as_float(((unsigned)h) << 16);
}

// ---------------- k1a: weight conversion ----------------
__global__ void prep_convert(const float* __restrict__ wgw, const float* __restrict__ wih,
                             const float* __restrict__ whh,
                             unsigned short* __restrict__ wgw_bf, unsigned short* __restrict__ wih_bf,
                             unsigned short* __restrict__ whh_bf)
{
  const int n1 = DD*DD, n2 = NIH*DD, n3 = NIH*HH;
  int stride = gridDim.x * 256;
  for (int idx = blockIdx.x*256 + threadIdx.x; idx < n1+n2+n3; idx += stride) {
    if (idx < n1)            wgw_bf[idx]       = f2bf(wgw[idx]);
    else if (idx < n1+n2)    wih_bf[idx-n1]    = f2bf(wih[idx-n1]);
    else                     whh_bf[idx-n1-n2] = f2bf(whh[idx-n1-n2]);
  }
}

// ---------------- k1b: vL = Wg_w^T aL, vR = Wg_w^T aR, c0/c1 ----------------
__global__ void prep_vecs(const float* __restrict__ wgw, const float* __restrict__ wgb,
                          const float* __restrict__ aL, const float* __restrict__ aR,
                          float* __restrict__ vLR, float* __restrict__ c01)
{
  int tid = threadIdx.x;
  if (blockIdx.x < 3) {
    int j = blockIdx.x*256 + tid;   // 0..767
    float al = 0.f, ar = 0.f;
    for (int i = 0; i < DD; ++i) { float wv = wgw[i*DD + j]; al += wv*aL[i]; ar += wv*aR[i]; }
    vLR[j] = al; vLR[DD + j] = ar;
  } else {
    float al = 0.f, ar = 0.f;
    for (int i = tid; i < DD; i += 256) { float bv = wgb[i]; al += bv*aL[i]; ar += bv*aR[i]; }
    for (int off = 32; off; off >>= 1) { al += __shfl_down(al, off); ar += __shfl_down(ar, off); }
    __shared__ float red[8];
    int w = tid >> 6, l = tid & 63;
    if (l == 0) { red[w*2] = al; red[w*2+1] = ar; }
    __syncthreads();
    if (tid == 0) { c01[0] = red[0]+red[2]+red[4]+red[6]; c01[1] = red[1]+red[3]+red[5]+red[7]; }
  }
}

// ---------------- k2: exact f32 attention scores ----------------
__global__ __launch_bounds__(256) void scores_cvt(const float* __restrict__ emb,
    const float* __restrict__ vLR, const float* __restrict__ c01,
    float* __restrict__ ss, float* __restrict__ sr)
{
  int row = blockIdx.x, tid = threadIdx.x;
  const float* er = emb + (size_t)row*DD;
  float al = 0.f, ar = 0.f;
  for (int d = tid; d < DD; d += 256) {
    float e = er[d];
    al += e*vLR[d]; ar += e*vLR[DD+d];
  }
  for (int off = 32; off; off >>= 1) { al += __shfl_down(al, off); ar += __shfl_down(ar, off); }
  __shared__ float red[8];
  int w = tid >> 6, l = tid & 63;
  if (l == 0) { red[w*2] = al; red[w*2+1] = ar; }
  __syncthreads();
  if (tid == 0) {
    ss[row] = red[0]+red[2]+red[4]+red[6] + c01[0];
    sr[row] = red[1]+red[3]+red[5]+red[7] + c01[1];
  }
}

// ---------------- GEMM: C[m,n] = sum_k A[m,k]*Bw[n,k] + bias[n] ----------------
template<bool AF32>
__global__ __launch_bounds__(256) void gemm_bt(const void* __restrict__ Av,
    const unsigned short* __restrict__ Bw, const float* __restrict__ bias,
    unsigned short* __restrict__ C, int N, int MT, int Mreal)
{
  __shared__ __align__(16) unsigned short As[128][32];
  __shared__ __align__(16) unsigned short Bs[128][32];
  int tid = threadIdx.x;
  int tm = blockIdx.x % MT, tn = blockIdx.x / MT;
  int l = tid & 63, lr = l & 15, lk = l >> 4;
  int w = tid >> 6;
  int wm = (w >> 1)*64, wn = (w & 1)*64;
  f32x4 acc[4][4] = {};

  int c0 = tid, c1 = tid + 256;            // 512 16B-chunks per tile
  int r0 = c0 >> 2, ch0 = c0 & 3;
  int r1 = c1 >> 2, ch1 = c1 & 3;
  const unsigned short* Bbase = Bw + (size_t)tn*128*DD;

  for (int kt = 0; kt < 24; ++kt) {
    short8 va0, va1;
    if constexpr (AF32) {
      const float* Af = (const float*)Av + (size_t)tm*128*DD;
      f32x4 a0l = *(const f32x4*)(Af + r0*DD + kt*32 + ch0*8);
      f32x4 a0h = *(const f32x4*)(Af + r0*DD + kt*32 + ch0*8 + 4);
      f32x4 a1l = *(const f32x4*)(Af + r1*DD + kt*32 + ch1*8);
      f32x4 a1h = *(const f32x4*)(Af + r1*DD + kt*32 + ch1*8 + 4);
      #pragma unroll
      for (int j = 0; j < 4; ++j) {
        va0[j] = (short)f2bf(a0l[j]); va0[4+j] = (short)f2bf(a0h[j]);
        va1[j] = (short)f2bf(a1l[j]); va1[4+j] = (short)f2bf(a1h[j]);
      }
    } else {
      const unsigned short* Ab = (const unsigned short*)Av + (size_t)tm*128*DD;
      va0 = *(const short8*)(Ab + r0*DD + kt*32 + ch0*8);
      va1 = *(const short8*)(Ab + r1*DD + kt*32 + ch1*8);
    }
    short8 vb0 = *(const short8*)(Bbase + r0*DD + kt*32 + ch0*8);
    short8 vb1 = *(const short8*)(Bbase + r1*DD + kt*32 + ch1*8);
    __syncthreads();                        // previous compute done
    *(short8*)&As[r0][(ch0 ^ (r0&3))*8] = va0;
    *(short8*)&As[r1][(ch1 ^ (r1&3))*8] = va1;
    *(short8*)&Bs[r0][(ch0 ^ (r0&3))*8] = vb0;
    *(short8*)&Bs[r1][(ch1 ^ (r1&3))*8] = vb1;
    __syncthreads();
    bf16x8 af[4], bfr[4];
    #pragma unroll
    for (int mi = 0; mi < 4; ++mi) {
      int r = wm + mi*16 + lr;
      af[mi] = __builtin_bit_cast(bf16x8, *(const short8*)&As[r][(lk ^ (lr&3))*8]);
    }
    #pragma unroll
    for (int ni = 0; ni < 4; ++ni) {
      int r = wn + ni*16 + lr;
      bfr[ni] = __builtin_bit_cast(bf16x8, *(const short8*)&Bs[r][(lk ^ (lr&3))*8]);
    }
    #pragma unroll
    for (int mi = 0; mi < 4; ++mi)
      #pragma unroll
      for (int ni = 0; ni < 4; ++ni)
        acc[mi][ni] = __builtin_amdgcn_mfma_f32_16x16x32_bf16(af[mi], bfr[ni], acc[mi][ni], 0, 0, 0);
  }
  // epilogue: D layout col=lane&15, row=(lane>>4)*4+reg
  for (int mi = 0; mi < 4; ++mi) {
    int rbase = tm*128 + wm + mi*16 + lk*4;
    for (int ni = 0; ni < 4; ++ni) {
      int col = tn*128 + wn + ni*16 + lr;
      float bv = bias[col];
      #pragma unroll
      for (int jr = 0; jr < 4; ++jr) {
        int row = rbase + jr;
        if (row < Mreal) C[(size_t)row*N + col] = f2bf(acc[mi][ni][jr] + bv);
      }
    }
  }
}

// ---------------- k4: GAT attention (exact f32 scores) + build G_W (bf16) ----------------
__global__ __launch_bounds__(256) void gat_attn(const float* __restrict__ emb,
    const float* __restrict__ cls, const unsigned short* __restrict__ wgt_bf,
    const float* __restrict__ ss, const float* __restrict__ sr,
    const int* __restrict__ cidx, const int* __restrict__ cmask,
    unsigned short* __restrict__ gw_bf)
{
  int bx = blockIdx.x, tid = threadIdx.x;
  if (bx >= BB*TT) {                       // CLS rows
    int b = bx - BB*TT;
    unsigned short* dst = gw_bf + (size_t)(b*(TT+1))*DD;
    for (int d = tid; d < DD; d += 256) dst[d] = f2bf(cls[d]);
    return;
  }
  int b = bx >> 10, t = bx & 1023;
  __shared__ float sw[8];
  __shared__ int   si[8];
  __shared__ int   sm[8];
  if (tid < 8) {
    int ci = cidx[(size_t)bx*8 + tid];
    int cm = cmask[(size_t)bx*8 + tid];
    float s = ss[bx] + sr[(b<<10) + ci];
    s = s > 0.f ? s : 0.2f*s;              // leaky_relu(0.2)
    sw[tid] = cm ? s : -1e9f;
    si[tid] = ci;
    sm[tid] = cm;
  }
  __syncthreads();
  float a[8];
  float mx = -1e30f;
  #pragma unroll
  for (int k = 0; k < 8; ++k) mx = fmaxf(mx, sw[k]);
  float sum = 0.f;
  #pragma unroll
  for (int k = 0; k < 8; ++k) { a[k] = expf(sw[k]-mx); sum += a[k]; }
  float inv = 1.f/sum;
  #pragma unroll
  for (int k = 0; k < 8; ++k) a[k] = sm[k] ? a[k]*inv : 0.f;
  const float* er = emb + (size_t)bx*DD;
  unsigned short* dst = gw_bf + (size_t)(b*(TT+1) + t + 1)*DD;
  for (int d = tid; d < DD; d += 256) {
    float acc = er[d];
    #pragma unroll
    for (int k = 0; k < 8; ++k)
      if (a[k] != 0.f) acc += a[k]*bf2f(wgt_bf[((size_t)(b<<10) + si[k])*DD + d]);
    dst[d] = f2bf(acc);
  }
}

// ---------------- k6: GRU scan v3 ----------------
// 3 WGs/batch. Per step: own-k MFMA overlaps the remote h flight; remote
// MFMA split into two 4-deep chains; tag-in-word per-step slots (relaxed
// agent atomics, one wire round-trip); fast __expf gates.
__global__ __launch_bounds__(512, 2) void gru_scan(const unsigned short* __restrict__ whh_bf,
    const float* __restrict__ bhh, const unsigned short* __restrict__ xp,
    const int* __restrict__ clue, unsigned* __restrict__ hbuf,
    float* __restrict__ hfinal)
{
  __shared__ __align__(16) unsigned short h_bf[HH];
  __shared__ __align__(16) float y_s[HH];
  __shared__ float bhh_s[HH];
  __shared__ unsigned char m_s[TT+1];
  int tid = threadIdx.x;
  // blocks b, b+16, b+32 land on the same XCD under round-robin dispatch
  int b = blockIdx.x % BB, g = blockIdx.x % GSP == blockIdx.x / BB ? blockIdx.x / BB : blockIdx.x / BB; // g = 0..2
  g = blockIdx.x / BB;
  int w = tid >> 6, l = tid & 63, lr = l & 15, lk = l >> 4;

  // areg slot c holds k-chunk kt=(g*4+c)%12  ->  own chunks are always c=0..3
  bf16x8 areg[3][12];
  #pragma unroll
  for (int i = 0; i < 3; ++i) {
    int nt = w*3 + i;                       // 0..23 (8 row-groups per gate)
    int gate = nt >> 3;
    int il = (nt & 7)*16 + lr;
    const unsigned short* src = whh_bf + (size_t)(gate*HH + g*128 + il)*HH;
    #pragma unroll
    for (int c = 0; c < 12; ++c) {
      int kt = g*4 + c; if (kt >= 12) kt -= 12;
      areg[i][c] = __builtin_bit_cast(bf16x8, *(const short8*)(src + kt*32 + lk*8));
    }
  }
  if (tid < HH) {
    int gate = tid >> 7, il = tid & 127;
    bhh_s[tid] = bhh[gate*HH + g*128 + il];
    h_bf[tid] = 0;
  }
  for (int t = tid; t < TT; t += 512) m_s[t+1] = (clue[b*TT + t] != 0) ? 1 : 0;
  if (tid == 0) m_s[0] = 1;
  __syncthreads();

  float h_prev = 0.f;                       // this thread's own h element (tid<128)
  int s = 0;
  int j = tid & 255;                        // 2 pollers per remote word
  int rj = g*128 + 128 + j; if (rj >= HH) rj -= HH;
  for (int t = 0; t <= TT; ++t) {
    if (!m_s[t]) continue;                  // masked step: h unchanged, skip entirely
    ++s;
    float xr = 0.f, xz = 0.f, xn = 0.f;
    if (tid < 128) {                        // x_proj loads: consumed only in phase 5
      const unsigned short* xrow = xp + (size_t)(b*(TT+1) + t)*NIH;
      int gi = g*128 + tid;
      xr = bf2f(xrow[gi]); xz = bf2f(xrow[HH + gi]); xn = bf2f(xrow[2*HH + gi]);
    }
    // phase 1: own-k MFMA on state s-1 (no remote dependency; overlaps flight)
    f32x4 aco[3] = {};
    #pragma unroll
    for (int c = 0; c < 4; ++c) {
      bf16x8 bfr = __builtin_bit_cast(bf16x8, *(const short8*)&h_bf[g*128 + c*32 + lk*8]);
      #pragma unroll
      for (int i = 0; i < 3; ++i)
        aco[i] = __builtin_amdgcn_mfma_f32_16x16x32_bf16(areg[i][c], bfr, aco[i], 0, 0, 0);
    }
    // phase 2: fetch remote 256 elements of state s-1
    if (s > 1) {
      unsigned* pslot = hbuf + ((size_t)(s-1)*BB + b)*HH;
      unsigned v = __hip_atomic_load(pslot + rj, __ATOMIC_RELAXED, __HIP_MEMORY_SCOPE_AGENT);
      while ((v & 0xFFFFu) != (unsigned)(s-1))
        v = __hip_atomic_load(pslot + rj, __ATOMIC_RELAXED, __HIP_MEMORY_SCOPE_AGENT);
      h_bf[rj] = (unsigned short)(v >> 16);
    }
    __syncthreads();
    // phase 3: remote-k MFMA, two 4-deep chains
    f32x4 acA[3] = {}, acB[3] = {};
    #pragma unroll
    for (int c = 4; c < 8; ++c) {
      int kk = g*128 + c*32; if (kk >= HH) kk -= HH;
      bf16x8 bfr = __builtin_bit_cast(bf16x8, *(const short8*)&h_bf[kk + lk*8]);
      #pragma unroll
      for (int i = 0; i < 3; ++i)
        acA[i] = __builtin_amdgcn_mfma_f32_16x16x32_bf16(areg[i][c], bfr, acA[i], 0, 0, 0);
    }
    #pragma unroll
    for (int c = 8; c < 12; ++c) {
      int kk = g*128 + c*32; if (kk >= HH) kk -= HH;
      bf16x8 bfr = __builtin_bit_cast(bf16x8, *(const short8*)&h_bf[kk + lk*8]);
      #pragma unroll
      for (int i = 0; i < 3; ++i)
        acB[i] = __builtin_amdgcn_mfma_f32_16x16x32_bf16(areg[i][c], bfr, acB[i], 0, 0, 0);
    }
    // phase 4: y handoff
    if (lr == 0) {
      #pragma unroll
      for (int i = 0; i < 3; ++i)
        *(f32x4*)&y_s[(w*3+i)*16 + lk*4] = aco[i] + acA[i] + acB[i];
    }
    __syncthreads();
    // phase 5: gates + publish
    unsigned* slot = hbuf + ((size_t)s*BB + b)*HH;
    if (tid < 128) {
      int il = tid, gi = g*128 + il;
      float hr = y_s[il]       + bhh_s[il];
      float hz = y_s[128+il]   + bhh_s[128+il];
      float hn = y_s[256+il]   + bhh_s[256+il];
      float rg = 1.f/(1.f + __expf(-(xr + hr)));
      float zg = 1.f/(1.f + __expf(-(xz + hz)));
      float a  = xn + rg*hn;
      a = fminf(fmaxf(a, -15.f), 15.f);
      float e2 = __expf(-2.f*a);
      float ng = (1.f - e2)/(1.f + e2);
      float hnew = (1.f - zg)*ng + zg*h_prev;
      h_prev = hnew;
      unsigned short hb16 = f2bf(hnew);
      h_bf[gi] = hb16;                      // own slice straight to LDS
      __hip_atomic_store(slot + gi, ((unsigned)hb16 << 16) | (unsigned)s,
                         __ATOMIC_RELAXED, __HIP_MEMORY_SCOPE_AGENT);
    }
    __syncthreads();                        // own slice ready for next phase-1
  }
  if (tid < 128) hfinal[b*HH + g*128 + tid] = h_prev;   // exact f32 slice
}

// ---------------- k6b: per-batch head contribution of h_clue ----------------
__global__ __launch_bounds__(384) void hpart_k(const float* __restrict__ hfinal,
    const float* __restrict__ Wc, const float* __restrict__ Wcb,
    const float* __restrict__ We, const float* __restrict__ Web, float* __restrict__ hpart)
{
  int b = blockIdx.x, tid = threadIdx.x;
  int j = tid >> 6, l = tid & 63;
  const float* wr = ((j < 3) ? (Wc + j*NIH) : (We + (j-3)*NIH)) + DD;
  float acc = 0.f;
  #pragma unroll
  for (int i = 0; i < 6; ++i) acc += hfinal[b*HH + l + i*64] * wr[l + i*64];
  for (int off = 32; off; off >>= 1) acc += __shfl_down(acc, off);
  if (l == 0) hpart[b*6 + j] = acc + ((j < 3) ? Wcb[j] : Web[j-3]);
}

// ---------------- k7: cause/effect heads ----------------
__global__ __launch_bounds__(256) void heads(const unsigned short* __restrict__ gw_bf,
    const float* __restrict__ Wc, const float* __restrict__ We,
    const float* __restrict__ hpart, float* __restrict__ out)
{
  __shared__ float Wl[6][DD];
  int tid = threadIdx.x;
  for (int idx = tid; idx < 6*DD; idx += 256) {
    int j = idx / DD, d = idx % DD;
    Wl[j][d] = (j < 3) ? Wc[j*NIH + d] : We[(j-3)*NIH + d];
  }
  __syncthreads();
  int w = tid >> 6, l = tid & 63;
  int row = blockIdx.x*4 + w;
  int b = row >> 10, t = row & 1023;
  const unsigned short* gr = gw_bf + (size_t)(b*(TT+1) + t + 1)*DD;
  float acc[6] = {0,0,0,0,0,0};
  for (int i = 0; i < 12; ++i) {
    int d = l + i*64;
    float v = bf2f(gr[d]);
    #pragma unroll
    for (int j = 0; j < 6; ++j) acc[j] += v * Wl[j][d];
  }
  #pragma unroll
  for (int j = 0; j < 6; ++j)
    for (int off = 32; off; off >>= 1) acc[j] += __shfl_down(acc[j], off);
  if (l == 0) {
    const float* hp = hpart + b*6;
    float* oc = out + (size_t)b*TT*3 + t*3;
    float* oe = out + (size_t)BB*TT*3 + (size_t)b*TT*3 + t*3;
    oc[0] = acc[0]+hp[0]; oc[1] = acc[1]+hp[1]; oc[2] = acc[2]+hp[2];
    oe[0] = acc[3]+hp[3]; oe[1] = acc[4]+hp[4]; oe[2] = acc[5]+hp[5];
  }
}

extern "C" void kernel_launch(void* const* d_in, const int* in_sizes, int n_in,
                              void* d_out, int out_size, void* d_ws, size_t ws_size,
                              hipStream_t stream)
{
  const float* emb  = (const float*)d_in[0];
  const float* cls  = (const float*)d_in[1];
  const float* wgw  = (const float*)d_in[2];
  const float* wgb  = (const float*)d_in[3];
  const float* aL   = (const float*)d_in[4];
  const float* aR   = (const float*)d_in[5];
  const float* wih  = (const float*)d_in[6];
  const float* bih  = (const float*)d_in[7];
  const float* whh  = (const float*)d_in[8];
  const float* bhh  = (const float*)d_in[9];
  const float* wcw  = (const float*)d_in[10];
  const float* wcb  = (const float*)d_in[11];
  const float* wew  = (const float*)d_in[12];
  const float* web  = (const float*)d_in[13];
  const int* cidx   = (const int*)d_in[14];
  const int* cmask  = (const int*)d_in[15];
  const int* clue   = (const int*)d_in[16];
  (void)in_sizes; (void)n_in; (void)out_size; (void)ws_size;

  char* ws = (char*)d_ws;
  size_t off = 0;
  auto alloc = [&](size_t bytes) { char* p = ws + off; off += (bytes + 255) & ~(size_t)255; return p; };
  // regionA: xp_bf (38MB); wgt_bf (25.2MB) aliases its head — disjoint lifetimes
  unsigned short* xp_bf  = (unsigned short*)alloc((size_t)16512*1152*2);
  unsigned short* wgt_bf = xp_bf;
  unsigned short* gw_bf  = (unsigned short*)alloc((size_t)16512*768*2);   // 129*128 rows padded
  unsigned short* wgw_bf = (unsigned short*)alloc((size_t)768*768*2);
  unsigned short* wih_bf = (unsigned short*)alloc((size_t)1152*768*2);
  unsigned short* whh_bf = (unsigned short*)alloc((size_t)1152*384*2);
  float* vLR   = (float*)alloc(1536*4);
  float* c01   = (float*)alloc(256);
  float* ss    = (float*)alloc(16384*4);
  float* sr    = (float*)alloc(16384*4);
  unsigned* hbuf = (unsigned*)alloc((size_t)(TT+2)*BB*HH*4);  // per-step tagged slots, 25.2MB
  float* hfin  = (float*)alloc((size_t)16*384*4);
  float* hpart = (float*)alloc(512);

  prep_convert<<<2048, 256, 0, stream>>>(wgw, wih, whh, wgw_bf, wih_bf, whh_bf);
  prep_vecs<<<4, 256, 0, stream>>>(wgw, wgb, aL, aR, vLR, c01);
  scores_cvt<<<16384, 256, 0, stream>>>(emb, vLR, c01, ss, sr);
  gemm_bt<true><<<128*6, 256, 0, stream>>>(emb, wgw_bf, wgb, wgt_bf, 768, 128, 16384);
  gat_attn<<<16384+16, 256, 0, stream>>>(emb, cls, wgt_bf, ss, sr, cidx, cmask, gw_bf);
  gemm_bt<false><<<129*9, 256, 0, stream>>>(gw_bf, wih_bf, bih, xp_bf, 1152, 129, 16400);
  gru_scan<<<BB*GSP, 512, 0, stream>>>(whh_bf, bhh, xp_bf, clue, hbuf, hfin);
  hpart_k<<<16, 384, 0, stream>>>(hfin, wcw, wcb, wew, web, hpart);
  heads<<<4096, 256, 0, stream>>>(gw_bf, wcw, wew, hpart, (float*)d_out);
}